// Round 1
// 591.948 us; speedup vs baseline: 1.0023x; 1.0023x over previous
//
#include <hip/hip_runtime.h>

// FastLoRAEmbedding: out[t,d] = weight[x[t],d] + 16 * sum_r A[r,x[t]] * B[d,r]
// x int32 [16384], weight f32 [50257,2048], lora_A f32 [64,50257],
// lora_B f32 [2048,64]. Output f32 [16384,2048].
//
// Strategy: the rank-64 correction is a [16384x64]x[64x2048] GEMM -> MFMA
// (bf16 inputs; |err| ~1e-3 << 1.2e-1 threshold). Base gather fused into the
// MFMA epilogue so the 134 MB output is written exactly once.
//
// R1 changes vs baseline (593 us):
//  - prep_b + gather_a merged into ONE launch (independent work, B-convert
//    hides under the A-gather; saves a dispatch + its graph gap).
//  - output stores are non-temporal: the 134 MB write stream is never
//    re-read, and the read working set (~115 MB unique weight rows + 13 MB
//    A table) is borderline vs the 256 MB L3 -- nt stores stop the output
//    from evicting weight rows that duplicate tokens re-hit.

constexpr int VOCAB = 50257;
constexpr int DIM = 2048;
constexpr int R = 64;
constexpr float SCALING = 16.0f;   // 128 / sqrt(64)

typedef short bf16x8 __attribute__((ext_vector_type(8)));  // 8 bf16 = 4 VGPRs
typedef float f32x4 __attribute__((ext_vector_type(4)));

__device__ inline unsigned short f32_to_bf16(float f) {
  unsigned int u = __builtin_bit_cast(unsigned int, f);
  u += 0x7FFFu + ((u >> 16) & 1u);    // round-to-nearest-even (inputs finite)
  return (unsigned short)(u >> 16);
}

// ws layout: [0, 256KB) b_bf16[DIM][R]; [256KB, 256KB+2MB) a_bf16[T][R]
constexpr size_t B_BF16_BYTES = (size_t)DIM * R * sizeof(unsigned short);
constexpr int B_QUADS = DIM * R / 4;          // 32768 ushort4 quads for B

// Kernel 1 (merged prep): first B_QUADS threads convert lora_B fp32->bf16
// ([d][r] row-major); remaining threads gather a_bf16[t][r] =
// bf16(lora_A[r*VOCAB + x[t]]) -- 4 scattered reads (12.9 MB table,
// L2/L3-resident), one coalesced 8-B store per thread.
__global__ __launch_bounds__(256) void prep_kernel(
    const int* __restrict__ x,
    const float* __restrict__ lora_A,
    const float* __restrict__ lora_B,
    unsigned short* __restrict__ a_bf16,
    unsigned short* __restrict__ b_bf16,
    int n_tokens) {
  int gid = blockIdx.x * 256 + threadIdx.x;
  if (gid < B_QUADS) {
    const float4 v = reinterpret_cast<const float4*>(lora_B)[gid];
    ushort4 o;
    o.x = f32_to_bf16(v.x); o.y = f32_to_bf16(v.y);
    o.z = f32_to_bf16(v.z); o.w = f32_to_bf16(v.w);
    reinterpret_cast<ushort4*>(b_bf16)[gid] = o;
  } else {
    int ag = gid - B_QUADS;                   // over n_tokens*R/4
    if (ag >= n_tokens * (R / 4)) return;
    int t = ag >> 4;                          // 16 quads per token
    int r4 = (ag & 15) * 4;
    int tok = x[t];
    ushort4 o;
    o.x = f32_to_bf16(lora_A[(size_t)(r4 + 0) * VOCAB + tok]);
    o.y = f32_to_bf16(lora_A[(size_t)(r4 + 1) * VOCAB + tok]);
    o.z = f32_to_bf16(lora_A[(size_t)(r4 + 2) * VOCAB + tok]);
    o.w = f32_to_bf16(lora_A[(size_t)(r4 + 3) * VOCAB + tok]);
    reinterpret_cast<ushort4*>(a_bf16)[ag] = o;
  }
}

// Kernel 2: block = 64 tokens x 64 dims, 4 waves; wave w owns tokens
// [tw0, tw0+16) x all 64 dims = 4 MFMA 16x16 tiles, K=64 in two k-halves.
// Frag layouts (gfx950, HW-verified per guide):
//   A[m][k]: m = lane&15, k = (lane>>4)*8 + j      (8 contiguous bf16)
//   B[k][n]: n = lane&15, k = (lane>>4)*8 + j      (8 contiguous bf16)
//   C/D:     col(n) = lane&15, row(m) = (lane>>4)*4 + reg
// Grid order note: blocks sharing a token-block (same blockIdx.x, y varying)
// are 256 apart -> same XCD (256 % 8 == 0), so their shared a_bf16 rows hit
// that XCD's L2.
__global__ __launch_bounds__(256) void fused_mfma_kernel(
    const int* __restrict__ x,
    const float* __restrict__ weight,
    const unsigned short* __restrict__ a_bf16,
    const unsigned short* __restrict__ b_bf16,
    float* __restrict__ out) {
  const int tid = threadIdx.x;
  const int wave = tid >> 6;
  const int lane = tid & 63;
  const int quad = lane >> 4;
  const int l16 = lane & 15;
  const int tw0 = blockIdx.x * 64 + wave * 16;
  const int d0 = blockIdx.y * 64;

  // A fragments (2 k-halves): 16-B loads from the token's contiguous a-row.
  bf16x8 aF[2];
#pragma unroll
  for (int h = 0; h < 2; ++h)
    aF[h] = *reinterpret_cast<const bf16x8*>(
        a_bf16 + (size_t)(tw0 + l16) * R + h * 32 + quad * 8);

  // B fragments (4 d-tiles x 2 k-halves): from the 256 KB L2-resident table.
  bf16x8 bF[4][2];
#pragma unroll
  for (int dt = 0; dt < 4; ++dt)
#pragma unroll
    for (int h = 0; h < 2; ++h)
      bF[dt][h] = *reinterpret_cast<const bf16x8*>(
          b_bf16 + (size_t)(d0 + dt * 16 + l16) * R + h * 32 + quad * 8);

  f32x4 acc[4];
#pragma unroll
  for (int dt = 0; dt < 4; ++dt) {
    acc[dt] = (f32x4){0.f, 0.f, 0.f, 0.f};
#pragma unroll
    for (int h = 0; h < 2; ++h)
      acc[dt] = __builtin_amdgcn_mfma_f32_16x16x32_bf16(
          aF[h], bF[dt][h], acc[dt], 0, 0, 0);
  }

  // Epilogue: row i covers token tw0+quad*4+i; 16 consecutive lanes hit 64 B
  // contiguous weight/out segments (4 segments per instruction). Out stores
  // are non-temporal (stream, never re-read) to preserve L3 residency of the
  // weight rows + staging tables.
#pragma unroll
  for (int i = 0; i < 4; ++i) {
    const int t = tw0 + quad * 4 + i;
    const int tok = x[t];
    const float* __restrict__ wrow = weight + (size_t)tok * DIM + d0 + l16;
    float* __restrict__ orow = out + (size_t)t * DIM + d0 + l16;
#pragma unroll
    for (int dt = 0; dt < 4; ++dt) {
      float v = wrow[dt * 16] + SCALING * acc[dt][i];
      __builtin_nontemporal_store(v, &orow[dt * 16]);
    }
  }
}

extern "C" void kernel_launch(void* const* d_in, const int* in_sizes, int n_in,
                              void* d_out, int out_size, void* d_ws, size_t ws_size,
                              hipStream_t stream) {
  const int* x = (const int*)d_in[0];
  const float* weight = (const float*)d_in[1];
  const float* lora_A = (const float*)d_in[2];
  const float* lora_B = (const float*)d_in[3];
  float* out = (float*)d_out;

  const int n_tokens = in_sizes[0];               // 16384
  unsigned short* b_bf16 = (unsigned short*)d_ws;
  unsigned short* a_bf16 = (unsigned short*)((char*)d_ws + B_BF16_BYTES);

  // Merged prep: B-convert quads first, then A-gather quads.
  const int total_quads = B_QUADS + n_tokens * (R / 4);
  prep_kernel<<<(total_quads + 255) / 256, 256, 0, stream>>>(
      x, lora_A, lora_B, a_bf16, b_bf16, n_tokens);

  dim3 grid(n_tokens / 64, DIM / 64);             // (256, 32) = 8192 blocks
  fused_mfma_kernel<<<grid, 256, 0, stream>>>(x, weight, a_bf16, b_bf16, out);
}